// Round 14
// baseline (70.873 us; speedup 1.0000x reference)
//
#include <hip/hip_runtime.h>
#include <hip/hip_bf16.h>
#include <stdint.h>

#define HW 192
#define NC 128
#define KEPS 1e-5f
#define SLICE_B 49152   /* bytes per image in frag layout */

typedef __attribute__((ext_vector_type(8))) short short8;
typedef __attribute__((ext_vector_type(4))) float f32x4;

__device__ __forceinline__ float max3f(float a, float b, float c) {
  float d;
  asm("v_max3_f32 %0, %1, %2, %3" : "=v"(d) : "v"(a), "v"(b), "v"(c));
  return d;
}

// ---------------------------------------------------------------------------
// Prep: f32 [n][C][HW] -> MFMA-fragment layout:
//   16B chunk (tile 0..11, ks 0..3, lane 0..63) at ((tile*4+ks)*64+lane)*16
//   holding img[c = ks*32 + (lane>>4)*8 + j][s = tile*16 + (lane&15)], j=0..7.
// ---------------------------------------------------------------------------
__global__ __launch_bounds__(256)
void prep_kernel(const float* __restrict__ prob,
                 const float* __restrict__ gal,
                 char* __restrict__ probF,
                 char* __restrict__ galF) {
  __shared__ unsigned short lds[32 * 194];
  const int b = blockIdx.x;
  const int slice = b >> 2;
  const int ks = b & 3;
  const bool isProbe = (slice < 64);
  const float* src = isProbe ? prob + (size_t)slice * NC * HW
                             : gal + (size_t)(slice - 64) * NC * HW;
  char* dstBase = isProbe ? probF + (size_t)slice * SLICE_B
                          : galF + (size_t)(slice - 64) * SLICE_B;
  const float* s0 = src + (size_t)(ks * 32) * HW;
  #pragma unroll
  for (int k = 0; k < 24; ++k) {
    int i = k * 256 + threadIdx.x;
    int cp = i / HW;
    int hw = i - cp * HW;
    lds[cp * 194 + hw] =
        __builtin_bit_cast(unsigned short, __float2bfloat16(s0[i]));
  }
  __syncthreads();
  #pragma unroll
  for (int rep = 0; rep < 3; ++rep) {
    int idx = rep * 256 + threadIdx.x;   // 0..767
    int tile = idx >> 6;
    int lane = idx & 63;
    int q = lane >> 4;
    int s = tile * 16 + (lane & 15);
    short8 pack;
    #pragma unroll
    for (int j = 0; j < 8; ++j)
      pack[j] = (short)lds[(q * 8 + j) * 194 + s];
    *(short8*)(dstBase + (((tile * 4 + ks) * 64 + lane) * 16)) = pack;
  }
}

template <int CTRL>
__device__ __forceinline__ float dpp_max(float x) {
  int xi = __builtin_bit_cast(int, x);
  int yi = __builtin_amdgcn_update_dpp(xi, xi, CTRL, 0xf, 0xf, false);
  return fmaxf(x, __builtin_bit_cast(float, yi));
}
__device__ __forceinline__ float ror16_max(float x) {
  x = dpp_max<0x121>(x);
  x = dpp_max<0x122>(x);
  x = dpp_max<0x124>(x);
  x = dpp_max<0x128>(x);
  return x;
}

// ---------------------------------------------------------------------------
// Pair kernel, dual-gallery on the R10 (proven) code shape:
// 2048 blocks = p*32 + gp; block computes pairs (p, 2gp) and (p, 2gp+1).
// 4 waves = 4 row-groups of 48; wave holds rows of BOTH galleries in regs
// (a0,a1 = 96 VGPR) -> every B quad feeds 24 MFMAs (B traffic halves).
// Barrier-free streaming from L1/L2 (frag layout, coalesced dwordx4);
// plain unrolled loops, static-indexed acc arrays.
// ---------------------------------------------------------------------------
__global__ __launch_bounds__(256, 2)
void pair_kernel(const char* __restrict__ galF,
                 const char* __restrict__ probF,
                 const float* __restrict__ fc_w,
                 float* __restrict__ Wout,
                 float* __restrict__ sPart,
                 float* __restrict__ qPart) {
  __shared__ float cmP[2][4][192];   // [gallery][wid][col] col-max partials
  __shared__ float rmF[2][192];      // [gallery][row] final row-max
  __shared__ float red[2][4];        // [gallery][wid] W partials
  __shared__ float red2[8];

  const int tid = threadIdx.x;
  const int lane = tid & 63;
  const int wid = tid >> 6;          // row group: rows wid*48..+47
  const int q = lane >> 4;
  const int r16 = lane & 15;

  const int p = blockIdx.x >> 5;     // probe
  const int gp = blockIdx.x & 31;    // gallery pair: galleries 2gp, 2gp+1

  // persistent A-frags for BOTH galleries
  const char* g0B = galF + (size_t)(2 * gp) * SLICE_B + lane * 16;
  const char* g1B = galF + (size_t)(2 * gp + 1) * SLICE_B + lane * 16;
  short8 a0[3][4], a1[3][4];
  #pragma unroll
  for (int m = 0; m < 3; ++m)
    #pragma unroll
    for (int ks = 0; ks < 4; ++ks) {
      a0[m][ks] = *(const short8*)(g0B + (((wid * 3 + m) * 4 + ks) * 1024));
      a1[m][ks] = *(const short8*)(g1B + (((wid * 3 + m) * 4 + ks) * 1024));
    }

  const float w0 = fc_w[tid];                           // feat j = tid
  const float w1 = (tid < 128) ? fc_w[256 + tid] : 0.f; // feat j = 256+tid

  const char* pB = probF + (size_t)p * SLICE_B + lane * 16;

  float rm0[3][4], rm1[3][4];
  float s_acc = 0.f, q_acc = 0.f;
  const f32x4 zz = (f32x4){0.f, 0.f, 0.f, 0.f};

  #pragma unroll 1
  for (int qt = 0; qt < 4; ++qt) {
    f32x4 acc0[3][3], acc1[3][3];
    __builtin_amdgcn_s_setprio(1);
    #pragma unroll
    for (int nt = 0; nt < 3; ++nt) {
      const char* bb = pB + ((qt * 3 + nt) * 4) * 1024;
      short8 b0 = *(const short8*)(bb);
      short8 b1 = *(const short8*)(bb + 1024);
      short8 b2 = *(const short8*)(bb + 2048);
      short8 b3 = *(const short8*)(bb + 3072);
      #pragma unroll
      for (int m = 0; m < 3; ++m)
        acc0[m][nt] = __builtin_amdgcn_mfma_f32_16x16x32_bf16(a0[m][0], b0, zz, 0, 0, 0);
      #pragma unroll
      for (int m = 0; m < 3; ++m)
        acc1[m][nt] = __builtin_amdgcn_mfma_f32_16x16x32_bf16(a1[m][0], b0, zz, 0, 0, 0);
      #pragma unroll
      for (int m = 0; m < 3; ++m)
        acc0[m][nt] = __builtin_amdgcn_mfma_f32_16x16x32_bf16(a0[m][1], b1, acc0[m][nt], 0, 0, 0);
      #pragma unroll
      for (int m = 0; m < 3; ++m)
        acc1[m][nt] = __builtin_amdgcn_mfma_f32_16x16x32_bf16(a1[m][1], b1, acc1[m][nt], 0, 0, 0);
      #pragma unroll
      for (int m = 0; m < 3; ++m)
        acc0[m][nt] = __builtin_amdgcn_mfma_f32_16x16x32_bf16(a0[m][2], b2, acc0[m][nt], 0, 0, 0);
      #pragma unroll
      for (int m = 0; m < 3; ++m)
        acc1[m][nt] = __builtin_amdgcn_mfma_f32_16x16x32_bf16(a1[m][2], b2, acc1[m][nt], 0, 0, 0);
      #pragma unroll
      for (int m = 0; m < 3; ++m)
        acc0[m][nt] = __builtin_amdgcn_mfma_f32_16x16x32_bf16(a0[m][3], b3, acc0[m][nt], 0, 0, 0);
      #pragma unroll
      for (int m = 0; m < 3; ++m)
        acc1[m][nt] = __builtin_amdgcn_mfma_f32_16x16x32_bf16(a1[m][3], b3, acc1[m][nt], 0, 0, 0);
    }
    __builtin_amdgcn_s_setprio(0);

    // ---- col-max per gallery over this wave's 48 rows ----
    #pragma unroll
    for (int nt = 0; nt < 3; ++nt) {
      {
        float m0 = max3f(acc0[0][nt][0], acc0[0][nt][1], acc0[0][nt][2]);
        float m1 = max3f(acc0[0][nt][3], acc0[1][nt][0], acc0[1][nt][1]);
        float m2 = max3f(acc0[1][nt][2], acc0[1][nt][3], acc0[2][nt][0]);
        float m3 = max3f(acc0[2][nt][1], acc0[2][nt][2], acc0[2][nt][3]);
        float cm = fmaxf(max3f(m0, m1, m2), m3);
        cm = fmaxf(cm, __shfl_xor(cm, 16));
        cm = fmaxf(cm, __shfl_xor(cm, 32));
        if (lane < 16) cmP[0][wid][qt * 48 + nt * 16 + r16] = cm;
      }
      {
        float m0 = max3f(acc1[0][nt][0], acc1[0][nt][1], acc1[0][nt][2]);
        float m1 = max3f(acc1[0][nt][3], acc1[1][nt][0], acc1[1][nt][1]);
        float m2 = max3f(acc1[1][nt][2], acc1[1][nt][3], acc1[2][nt][0]);
        float m3 = max3f(acc1[2][nt][1], acc1[2][nt][2], acc1[2][nt][3]);
        float cm = fmaxf(max3f(m0, m1, m2), m3);
        cm = fmaxf(cm, __shfl_xor(cm, 16));
        cm = fmaxf(cm, __shfl_xor(cm, 32));
        if (lane < 16) cmP[1][wid][qt * 48 + nt * 16 + r16] = cm;
      }
    }
    // ---- row-max: fold over nt in-lane, carry across quarters ----
    #pragma unroll
    for (int m = 0; m < 3; ++m)
      #pragma unroll
      for (int j = 0; j < 4; ++j) {
        float v0 = max3f(acc0[m][0][j], acc0[m][1][j], acc0[m][2][j]);
        float v1 = max3f(acc1[m][0][j], acc1[m][1][j], acc1[m][2][j]);
        rm0[m][j] = (qt == 0) ? v0 : fmaxf(rm0[m][j], v0);
        rm1[m][j] = (qt == 0) ? v1 : fmaxf(rm1[m][j], v1);
      }
  }

  // finish row-max: 16-lane DPP fold, publish rows wid*48 + m*16 + q*4 + j
  #pragma unroll
  for (int m = 0; m < 3; ++m)
    #pragma unroll
    for (int j = 0; j < 4; ++j) {
      float v0 = ror16_max(rm0[m][j]);
      float v1 = ror16_max(rm1[m][j]);
      if (r16 == j) {
        rmF[0][wid * 48 + m * 16 + q * 4 + j] = v0;
        rmF[1][wid * 48 + m * 16 + q * 4 + j] = v1;
      }
    }

  __syncthreads();   // all partials visible

  // ---- combine: both galleries (R10 combine with pi -> gi) ----
  #pragma unroll
  for (int gi = 0; gi < 2; ++gi) {
    float v;
    if (tid < 192) {
      float c01 = fmaxf(cmP[gi][0][tid], cmP[gi][1][tid]);
      v = max3f(c01, cmP[gi][2][tid], cmP[gi][3][tid]);
    } else {
      v = rmF[gi][tid - 192];          // rows 0..63 -> feat j = tid
    }
    s_acc += v; q_acc += v * v;
    float w = v * w0;
    if (tid < 128) {
      float v1 = rmF[gi][tid + 64];    // rows 64..191 -> feat j = 256+tid
      s_acc += v1; q_acc += v1 * v1;
      w += v1 * w1;
    }
    #pragma unroll
    for (int msk = 1; msk < 64; msk <<= 1) w += __shfl_xor(w, msk);
    if (lane == 0) red[gi][wid] = w;
  }
  #pragma unroll
  for (int msk = 1; msk < 64; msk <<= 1) {
    s_acc += __shfl_xor(s_acc, msk);
    q_acc += __shfl_xor(q_acc, msk);
  }
  if (lane == 0) { red2[wid] = s_acc; red2[4 + wid] = q_acc; }
  __syncthreads();
  if (tid < 2)
    Wout[p * 64 + 2 * gp + tid] =
        red[tid][0] + red[tid][1] + red[tid][2] + red[tid][3];
  if (tid == 0) {
    sPart[blockIdx.x] = red2[0] + red2[1] + red2[2] + red2[3];
    qPart[blockIdx.x] = red2[4] + red2[5] + red2[6] + red2[7];
  }
}

// ---------------------------------------------------------------------------
// Finalize: exact BN -> fc -> BN chain. One block, 1024 threads.
// sPart/qPart have 2048 entries.
// ---------------------------------------------------------------------------
__device__ __forceinline__ float block_sum(float v, float* rbuf, float* bc, int nw) {
  int t = threadIdx.x, lane = t & 63, wid = t >> 6;
  #pragma unroll
  for (int m = 1; m < 64; m <<= 1) v += __shfl_xor(v, m);
  if (lane == 0) rbuf[wid] = v;
  __syncthreads();
  if (t == 0) {
    float r = 0.f;
    for (int i = 0; i < nw; ++i) r += rbuf[i];
    bc[0] = r;
  }
  __syncthreads();
  float res = bc[0];
  __syncthreads();
  return res;
}

__global__ __launch_bounds__(1024)
void finalize_kernel(const float* __restrict__ Wv,
                     const float* __restrict__ sPart,
                     const float* __restrict__ qPart,
                     const float* __restrict__ fc_w,
                     const float* __restrict__ fc_b,
                     const float* __restrict__ bn_g,
                     const float* __restrict__ bn_b,
                     const float* __restrict__ lbn_g,
                     const float* __restrict__ lbn_b,
                     float* __restrict__ out) {
  __shared__ float rbuf[16];
  __shared__ float bc[1];
  const int t = threadIdx.x;

  float S = block_sum(sPart[t] + sPart[t + 1024], rbuf, bc, 16);
  float Q = block_sum(qPart[t] + qPart[t + 1024], rbuf, bc, 16);
  float SW = block_sum((t < 384) ? fc_w[t] : 0.f, rbuf, bc, 16);

  const float Nf = 4096.0f * 384.0f;
  float mu = S / Nf;
  float var = Q / Nf - mu * mu;
  float istd = rsqrtf(var + KEPS);
  float cA = istd * bn_g[0];
  float off = bn_b[0] * SW + fc_b[0] - cA * mu * SW;

  float l[4];
  float ls = 0.f;
  #pragma unroll
  for (int i = 0; i < 4; ++i) {
    int n = t + i * 1024;
    l[i] = cA * Wv[n] + off;
    ls += l[i];
  }
  float LS = block_sum(ls, rbuf, bc, 16);
  float lmu = LS / 4096.0f;
  float lq = 0.f;
  #pragma unroll
  for (int i = 0; i < 4; ++i) { float d = l[i] - lmu; lq += d * d; }
  float LQ = block_sum(lq, rbuf, bc, 16);
  float lvar = LQ / 4096.0f;
  float sc = lbn_g[0] * rsqrtf(lvar + KEPS);
  float lb = lbn_b[0];
  #pragma unroll
  for (int i = 0; i < 4; ++i) {
    int n = t + i * 1024;
    out[n] = (l[i] - lmu) * sc + lb;
  }
}

// ---------------------------------------------------------------------------
extern "C" void kernel_launch(void* const* d_in, const int* in_sizes, int n_in,
                              void* d_out, int out_size, void* d_ws, size_t ws_size,
                              hipStream_t stream) {
  const float* prob  = (const float*)d_in[0];
  const float* gal   = (const float*)d_in[1];
  const float* bn_g  = (const float*)d_in[2];
  const float* bn_b  = (const float*)d_in[3];
  const float* fc_w  = (const float*)d_in[4];
  const float* fc_b  = (const float*)d_in[5];
  const float* lbn_g = (const float*)d_in[6];
  const float* lbn_b = (const float*)d_in[7];
  float* out = (float*)d_out;

  char* ws = (char*)d_ws;
  char* probF = ws;                                  // 3,145,728 B
  char* galF  = ws + 3145728;                        // 3,145,728 B
  float* Wv    = (float*)(ws + 6291456);             // 16384 B
  float* sPart = (float*)(ws + 6307840);             // 8192 B
  float* qPart = (float*)(ws + 6316032);             // 8192 B

  prep_kernel<<<512, 256, 0, stream>>>(prob, gal, probF, galF);
  pair_kernel<<<2048, 256, 0, stream>>>(galF, probF, fc_w, Wv, sPart, qPart);
  finalize_kernel<<<1, 1024, 0, stream>>>(Wv, sPart, qPart, fc_w, fc_b,
                                          bn_g, bn_b, lbn_g, lbn_b, out);
}